// Round 8
// baseline (1202.602 us; speedup 1.0000x reference)
//
#include <hip/hip_runtime.h>

#define BB 4
#define NN 8192
#define QW 4          // queries per wave (wave-independent, no split)
#define QB 16         // queries per block (4 waves)
#define CAP 64        // survivor capacity per query
#define NPAIRS 4096   // candidate pairs per batch (N/2)

typedef unsigned long long u64;
typedef unsigned int u32;
typedef float v2f __attribute__((ext_vector_type(2)));

__device__ __forceinline__ u64 shfl_xor_u64(u64 v, int m) {
  u32 lo = (u32)v, hi = (u32)(v >> 32);
  lo = (u32)__shfl_xor((int)lo, m, 64);
  hi = (u32)__shfl_xor((int)hi, m, 64);
  return ((u64)hi << 32) | lo;
}
__device__ __forceinline__ u64 min_u64(u64 a, u64 b) { return a < b ? a : b; }

// fast filter distance: contracted pk math (|d' - d_exact| <= ~3e-5, covered by slack)
__device__ __forceinline__ v2f dist2_fast(float qx, float qy, float qz, float qw,
                                          v2f cx2, v2f cy2, v2f cz2, v2f cw2) {
#pragma clang fp contract(fast)
  return (qw + cw2) - 2.0f * (qx * cx2 + qy * cy2 + qz * cz2);
}

// np-exact distance (bit-matches reference; fma(-2,..) == t-2*inner exactly)
__device__ __forceinline__ float dist_exact(float4 q, float cx, float cy, float cz, float cw) {
#pragma clang fp contract(off)
  float inner = q.x * cx;
  inner = inner + q.y * cy;
  inner = inner + q.z * cz;
  float tt = q.w + cw;
  return __builtin_fmaf(-2.0f, inner, tt);
}

// ---- fused: zmat (blocks 0..1023, 32-j tiles) + coords prep (blocks 1024..1087) ----
__global__ void fused_prep_zmat(const float* __restrict__ x, const float* __restrict__ W,
                                const float* __restrict__ coords,
                                float* __restrict__ z,
                                float4* __restrict__ cpxy, float4* __restrict__ cpzw,
                                float* __restrict__ ycoords) {
#pragma clang fp contract(off)
  __shared__ float Ws[64 * 65];
  __shared__ float xs[64 * 32];
  int t = threadIdx.x;
  if (blockIdx.x < 1024) {
    int blk = blockIdx.x;
    int b = blk >> 8;                 // 256 blocks per batch
    int j0 = (blk & 255) * 32;
    for (int r = t; r < 4096; r += 256) Ws[(r >> 6) * 65 + (r & 63)] = W[r];
    const float* xb = x + (size_t)b * 64 * NN;
    for (int r = 0; r < 8; ++r) {
      int idx = t + r * 256;
      int c = idx >> 5, j = idx & 31;
      xs[c * 32 + j] = xb[(size_t)c * NN + j0 + j];
    }
    __syncthreads();
    int o = t & 63, jb = (t >> 6) * 8;
    float acc[8];
#pragma unroll
    for (int m = 0; m < 8; ++m) acc[m] = 0.f;
    for (int c = 0; c < 64; ++c) {
      float w = Ws[o * 65 + c];
#pragma unroll
      for (int m = 0; m < 8; ++m) acc[m] = __builtin_fmaf(w, xs[c * 32 + jb + m], acc[m]);
    }
#pragma unroll
    for (int m = 0; m < 8; ++m)
      z[((size_t)b * NN + j0 + jb + m) * 64 + o] = acc[m];
  } else {
    int t2 = (blockIdx.x - 1024) * 256 + t;   // [0, 16384) candidate pairs
    int b = t2 >> 12;
    int pl = t2 & 4095;
    int j0 = 2 * pl;
    const float* cb = coords + (size_t)b * 3 * NN;
    float x0 = cb[j0],          x1 = cb[j0 + 1];
    float y0 = cb[NN + j0],     y1 = cb[NN + j0 + 1];
    float z0 = cb[2 * NN + j0], z1 = cb[2 * NN + j0 + 1];
    float sq0 = (x0 * x0 + y0 * y0) + z0 * z0;   // np-exact sequential fp32
    float sq1 = (x1 * x1 + y1 * y1) + z1 * z1;
    float4 pxy; pxy.x = x0; pxy.y = x1; pxy.z = y0; pxy.w = y1;
    float4 pzw; pzw.x = z0; pzw.y = z1; pzw.z = sq0; pzw.w = sq1;
    cpxy[(size_t)b * NPAIRS + pl] = pxy;
    cpzw[(size_t)b * NPAIRS + pl] = pzw;
#pragma unroll
    for (int r = 0; r < 6; ++r)
      ycoords[r * 16384 + t2] = coords[r * 16384 + t2];  // coords passthrough
  }
}

// ---- KNN: wave = 4 queries, full candidate scan, wave-independent; + fused gather ----
__global__ void __launch_bounds__(256, 8) knn_gather(const float4* __restrict__ cpxy,
                                                     const float4* __restrict__ cpzw,
                                                     const float* __restrict__ z,
                                                     float* __restrict__ y) {
  __shared__ u64 surv[QB][CAP];     // 8 KB
  __shared__ int scnt[QB];
  __shared__ int sidx[QB][16];      // 1 KB
  __shared__ float ys[64][QB + 1];  // 4.25 KB
  int t = threadIdx.x;
  int w = t >> 6, lane = t & 63;
  int qbase = blockIdx.x * QB;
  int b = qbase >> 13;
  const float4* pxy = cpxy + (size_t)b * NPAIRS;
  const float4* pzw = cpzw + (size_t)b * NPAIRS;

  if (lane < QW) scnt[w * QW + lane] = 0;   // wave-local state: no barrier needed

  // queries from the pair-SoA planes
  float4 qc[QW];
#pragma unroll
  for (int qi = 0; qi < QW; ++qi) {
    int qloc = (qbase & (NN - 1)) + w * QW + qi;
    float4 a  = pxy[qloc >> 1];
    float4 bz = pzw[qloc >> 1];
    int par = qloc & 1;
    qc[qi].x = par ? a.y : a.x;
    qc[qi].y = par ? a.w : a.z;
    qc[qi].z = par ? bz.y : bz.x;
    qc[qi].w = par ? bz.w : bz.z;
  }

  // ---- pass A: per-lane min of fast distance over all candidates ----
  v2f bestd[QW];
#pragma unroll
  for (int qi = 0; qi < QW; ++qi) bestd[qi] = (v2f){3.402823466e+38f, 3.402823466e+38f};

#pragma unroll 2
  for (int s = 0; s < NPAIRS / 64; ++s) {
    float4 cxy = pxy[s * 64 + lane];   // {x0,x1,y0,y1}
    float4 czw = pzw[s * 64 + lane];   // {z0,z1,sq0,sq1}
    v2f cx2 = {cxy.x, cxy.y}, cy2 = {cxy.z, cxy.w};
    v2f cz2 = {czw.x, czw.y}, cw2 = {czw.z, czw.w};
#pragma unroll
    for (int qi = 0; qi < QW; ++qi) {
      v2f d2 = dist2_fast(qc[qi].x, qc[qi].y, qc[qi].z, qc[qi].w, cx2, cy2, cz2, cw2);
      bestd[qi].x = fminf(bestd[qi].x, d2.x);
      bestd[qi].y = fminf(bestd[qi].y, d2.y);
    }
  }

  // ---- threshold (wave-local): 16th smallest of 64 per-lane minima + slack ----
  float Tf[QW];
#pragma unroll 1
  for (int qi = 0; qi < QW; ++qi) {
    float v = fminf(bestd[qi].x, bestd[qi].y);
#pragma unroll
    for (int k = 2; k <= 64; k <<= 1) {
#pragma unroll
      for (int jm = k >> 1; jm >= 1; jm >>= 1) {
        float o = __shfl_xor(v, jm, 64);
        bool keepmin = ((lane & jm) == 0) == ((lane & k) == 0);
        v = keepmin ? fminf(v, o) : fmaxf(v, o);
      }
    }
    float t16 = __shfl(v, 15, 64);   // full-wave shuffle (R6 lesson)
    Tf[qi] = t16 * 1.000001f + 1e-3f;  // slack >> 2*filter-rounding
  }

  // ---- pass B: fast filter, np-exact key only for survivors ----
#pragma unroll 2
  for (int s = 0; s < NPAIRS / 64; ++s) {
    float4 cxy = pxy[s * 64 + lane];
    float4 czw = pzw[s * 64 + lane];
    v2f cx2 = {cxy.x, cxy.y}, cy2 = {cxy.z, cxy.w};
    v2f cz2 = {czw.x, czw.y}, cw2 = {czw.z, czw.w};
    int j0 = (s * 64 + lane) * 2;
#pragma unroll
    for (int qi = 0; qi < QW; ++qi) {
      v2f d2 = dist2_fast(qc[qi].x, qc[qi].y, qc[qi].z, qc[qi].w, cx2, cy2, cz2, cw2);
      int ql = w * QW + qi;
      if (d2.x <= Tf[qi]) {
        float de = dist_exact(qc[qi], cxy.x, cxy.z, czw.x, czw.z);
        u32 f = __float_as_uint(de);
        u32 m32 = f ^ ((u32)(((int)f) >> 31) | 0x80000000u);
        int pos = atomicAdd(&scnt[ql], 1);
        if (pos < CAP) surv[ql][pos] = ((u64)m32 << 32) | (u32)j0;
      }
      if (d2.y <= Tf[qi]) {
        float de = dist_exact(qc[qi], cxy.y, cxy.w, czw.y, czw.w);
        u32 f = __float_as_uint(de);
        u32 m32 = f ^ ((u32)(((int)f) >> 31) | 0x80000000u);
        int pos = atomicAdd(&scnt[ql], 1);
        if (pos < CAP) surv[ql][pos] = ((u64)m32 << 32) | (u32)(j0 + 1);
      }
    }
  }

  // ---- exact top-16 per query (u64 bitonic), then gather — all wave-local ----
  const float* zb = z + (size_t)b * NN * 64;
#pragma unroll 1
  for (int qi = 0; qi < QW; ++qi) {
    int ql = w * QW + qi;
    int n = scnt[ql]; if (n > CAP) n = CAP;
    u64 v = (lane < n) ? surv[ql][lane] : ~0ull;
#pragma unroll
    for (int k = 2; k <= 64; k <<= 1) {
#pragma unroll
      for (int jm = k >> 1; jm >= 1; jm >>= 1) {
        u64 o = shfl_xor_u64(v, jm);
        bool keepmin = ((lane & jm) == 0) == ((lane & k) == 0);
        u64 mn = min_u64(v, o);
        u64 mx = (v < o) ? o : v;
        v = keepmin ? mn : mx;
      }
    }
    if (lane < 16) sidx[ql][lane] = (int)(v & 0xFFFFFFFFull);
  }
#pragma unroll 1
  for (int qi = 0; qi < QW; ++qi) {
    int ql = w * QW + qi;
    const int* id = sidx[ql];            // same-wave LDS, program-order safe
    float m = -3.402823466e+38f;
#pragma unroll
    for (int k = 0; k < 16; ++k)
      m = fmaxf(m, zb[(size_t)id[k] * 64 + lane]);   // coalesced 256B row
    ys[lane][ql] = m;
  }
  __syncthreads();   // only barrier: transpose for coalesced store
  int i0 = qbase & (NN - 1);
#pragma unroll
  for (int r = 0; r < 4; ++r) {
    int e = r * 256 + t;
    int o = e >> 4, ql = e & 15;
    y[((size_t)b * 64 + o) * NN + i0 + ql] = ys[o][ql];
  }
}

extern "C" void kernel_launch(void* const* d_in, const int* in_sizes, int n_in,
                              void* d_out, int out_size, void* d_ws, size_t ws_size,
                              hipStream_t stream) {
  const float* x      = (const float*)d_in[0];   // [B,64,N]
  const float* coords = (const float*)d_in[1];   // [B,3,N]
  const float* W      = (const float*)d_in[2];   // [64,64]
  float* y = (float*)d_out;                      // [B,64,N] then coords

  char* ws = (char*)d_ws;
  float4* cpxy = (float4*)ws;                    // 256 KB
  float4* cpzw = (float4*)(ws + (1u << 18));     // 256 KB
  float*  z    = (float*)(ws + (1u << 20));      // 8 MB

  float* ycoords = y + (size_t)BB * 64 * NN;

  fused_prep_zmat<<<1024 + 64, 256, 0, stream>>>(x, W, coords, z, cpxy, cpzw, ycoords);
  knn_gather<<<BB * NN / QB, 256, 0, stream>>>(cpxy, cpzw, z, y);
}

// Round 9
// 196.458 us; speedup vs baseline: 6.1214x; 6.1214x over previous
//
#include <hip/hip_runtime.h>

#define BB 4
#define NN 8192
#define QW 4          // queries per wave (wave-independent, no split)
#define QB 16         // queries per block (4 waves)
#define CAP 64        // survivor capacity per query
#define NPAIRS 4096   // candidate pairs per batch (N/2)

typedef unsigned long long u64;
typedef unsigned int u32;
typedef float v2f __attribute__((ext_vector_type(2)));

__device__ __forceinline__ u64 shfl_xor_u64(u64 v, int m) {
  u32 lo = (u32)v, hi = (u32)(v >> 32);
  lo = (u32)__shfl_xor((int)lo, m, 64);
  hi = (u32)__shfl_xor((int)hi, m, 64);
  return ((u64)hi << 32) | lo;
}
__device__ __forceinline__ u64 min_u64(u64 a, u64 b) { return a < b ? a : b; }

// fast filter distance: contracted pk math (|d' - d_exact| <= ~3e-5, covered by slack)
__device__ __forceinline__ v2f dist2_fast(float qx, float qy, float qz, float qw,
                                          v2f cx2, v2f cy2, v2f cz2, v2f cw2) {
#pragma clang fp contract(fast)
  return (qw + cw2) - 2.0f * (qx * cx2 + qy * cy2 + qz * cz2);
}

// np-exact distance (bit-matches reference; fma(-2,..) == t-2*inner exactly)
__device__ __forceinline__ float dist_exact(float4 q, float cx, float cy, float cz, float cw) {
#pragma clang fp contract(off)
  float inner = q.x * cx;
  inner = inner + q.y * cy;
  inner = inner + q.z * cz;
  float tt = q.w + cw;
  return __builtin_fmaf(-2.0f, inner, tt);
}

// ---- fused: zmat (blocks 0..1023, 32-j tiles) + coords prep (blocks 1024..1087) ----
__global__ void fused_prep_zmat(const float* __restrict__ x, const float* __restrict__ W,
                                const float* __restrict__ coords,
                                float* __restrict__ z,
                                float4* __restrict__ cpxy, float4* __restrict__ cpzw,
                                float* __restrict__ ycoords) {
#pragma clang fp contract(off)
  __shared__ float Ws[64 * 65];
  __shared__ float xs[64 * 32];
  int t = threadIdx.x;
  if (blockIdx.x < 1024) {
    int blk = blockIdx.x;
    int b = blk >> 8;                 // 256 blocks per batch
    int j0 = (blk & 255) * 32;
    for (int r = t; r < 4096; r += 256) Ws[(r >> 6) * 65 + (r & 63)] = W[r];
    const float* xb = x + (size_t)b * 64 * NN;
    for (int r = 0; r < 8; ++r) {
      int idx = t + r * 256;
      int c = idx >> 5, j = idx & 31;
      xs[c * 32 + j] = xb[(size_t)c * NN + j0 + j];
    }
    __syncthreads();
    int o = t & 63, jb = (t >> 6) * 8;
    float acc[8];
#pragma unroll
    for (int m = 0; m < 8; ++m) acc[m] = 0.f;
    for (int c = 0; c < 64; ++c) {
      float w = Ws[o * 65 + c];
#pragma unroll
      for (int m = 0; m < 8; ++m) acc[m] = __builtin_fmaf(w, xs[c * 32 + jb + m], acc[m]);
    }
#pragma unroll
    for (int m = 0; m < 8; ++m)
      z[((size_t)b * NN + j0 + jb + m) * 64 + o] = acc[m];
  } else {
    int t2 = (blockIdx.x - 1024) * 256 + t;   // [0, 16384) candidate pairs
    int b = t2 >> 12;
    int pl = t2 & 4095;
    int j0 = 2 * pl;
    const float* cb = coords + (size_t)b * 3 * NN;
    float x0 = cb[j0],          x1 = cb[j0 + 1];
    float y0 = cb[NN + j0],     y1 = cb[NN + j0 + 1];
    float z0 = cb[2 * NN + j0], z1 = cb[2 * NN + j0 + 1];
    float sq0 = (x0 * x0 + y0 * y0) + z0 * z0;   // np-exact sequential fp32
    float sq1 = (x1 * x1 + y1 * y1) + z1 * z1;
    float4 pxy; pxy.x = x0; pxy.y = x1; pxy.z = y0; pxy.w = y1;
    float4 pzw; pzw.x = z0; pzw.y = z1; pzw.z = sq0; pzw.w = sq1;
    cpxy[(size_t)b * NPAIRS + pl] = pxy;
    cpzw[(size_t)b * NPAIRS + pl] = pzw;
#pragma unroll
    for (int r = 0; r < 6; ++r)
      ycoords[r * 16384 + t2] = coords[r * 16384 + t2];  // coords passthrough
  }
}

// ---- KNN: wave = 4 queries, full candidate scan, wave-independent; + fused gather ----
// R8 POST-MORTEM: __launch_bounds__(256,8) forced VGPR to 32 -> 3.4 GB scratch
// spill (WRITE_SIZE), 5x regression. (256,4) caps at 128; natural alloc ~56-64
// gives 6-8 waves/SIMD with zero spill.
__global__ void __launch_bounds__(256, 4) knn_gather(const float4* __restrict__ cpxy,
                                                     const float4* __restrict__ cpzw,
                                                     const float* __restrict__ z,
                                                     float* __restrict__ y) {
  __shared__ u64 surv[QB][CAP];     // 8 KB
  __shared__ int scnt[QB];
  __shared__ int sidx[QB][16];      // 1 KB
  __shared__ float ys[64][QB + 1];  // 4.25 KB
  int t = threadIdx.x;
  int w = t >> 6, lane = t & 63;
  int qbase = blockIdx.x * QB;
  int b = qbase >> 13;
  const float4* pxy = cpxy + (size_t)b * NPAIRS;
  const float4* pzw = cpzw + (size_t)b * NPAIRS;

  if (lane < QW) scnt[w * QW + lane] = 0;   // wave-local state: no barrier needed

  // queries from the pair-SoA planes
  float4 qc[QW];
#pragma unroll
  for (int qi = 0; qi < QW; ++qi) {
    int qloc = (qbase & (NN - 1)) + w * QW + qi;
    float4 a  = pxy[qloc >> 1];
    float4 bz = pzw[qloc >> 1];
    int par = qloc & 1;
    qc[qi].x = par ? a.y : a.x;
    qc[qi].y = par ? a.w : a.z;
    qc[qi].z = par ? bz.y : bz.x;
    qc[qi].w = par ? bz.w : bz.z;
  }

  // ---- pass A: per-lane min of fast distance over all candidates ----
  v2f bestd[QW];
#pragma unroll
  for (int qi = 0; qi < QW; ++qi) bestd[qi] = (v2f){3.402823466e+38f, 3.402823466e+38f};

#pragma unroll 2
  for (int s = 0; s < NPAIRS / 64; ++s) {
    float4 cxy = pxy[s * 64 + lane];   // {x0,x1,y0,y1}
    float4 czw = pzw[s * 64 + lane];   // {z0,z1,sq0,sq1}
    v2f cx2 = {cxy.x, cxy.y}, cy2 = {cxy.z, cxy.w};
    v2f cz2 = {czw.x, czw.y}, cw2 = {czw.z, czw.w};
#pragma unroll
    for (int qi = 0; qi < QW; ++qi) {
      v2f d2 = dist2_fast(qc[qi].x, qc[qi].y, qc[qi].z, qc[qi].w, cx2, cy2, cz2, cw2);
      bestd[qi].x = fminf(bestd[qi].x, d2.x);
      bestd[qi].y = fminf(bestd[qi].y, d2.y);
    }
  }

  // ---- threshold (wave-local): 16th smallest of 64 per-lane minima + slack ----
  float Tf[QW];
#pragma unroll 1
  for (int qi = 0; qi < QW; ++qi) {
    float v = fminf(bestd[qi].x, bestd[qi].y);
#pragma unroll
    for (int k = 2; k <= 64; k <<= 1) {
#pragma unroll
      for (int jm = k >> 1; jm >= 1; jm >>= 1) {
        float o = __shfl_xor(v, jm, 64);
        bool keepmin = ((lane & jm) == 0) == ((lane & k) == 0);
        v = keepmin ? fminf(v, o) : fmaxf(v, o);
      }
    }
    float t16 = __shfl(v, 15, 64);   // full-wave shuffle (R6 lesson)
    Tf[qi] = t16 * 1.000001f + 1e-3f;  // slack >> 2*filter-rounding
  }

  // ---- pass B: fast filter, np-exact key only for survivors ----
#pragma unroll 2
  for (int s = 0; s < NPAIRS / 64; ++s) {
    float4 cxy = pxy[s * 64 + lane];
    float4 czw = pzw[s * 64 + lane];
    v2f cx2 = {cxy.x, cxy.y}, cy2 = {cxy.z, cxy.w};
    v2f cz2 = {czw.x, czw.y}, cw2 = {czw.z, czw.w};
    int j0 = (s * 64 + lane) * 2;
#pragma unroll
    for (int qi = 0; qi < QW; ++qi) {
      v2f d2 = dist2_fast(qc[qi].x, qc[qi].y, qc[qi].z, qc[qi].w, cx2, cy2, cz2, cw2);
      int ql = w * QW + qi;
      if (d2.x <= Tf[qi]) {
        float de = dist_exact(qc[qi], cxy.x, cxy.z, czw.x, czw.z);
        u32 f = __float_as_uint(de);
        u32 m32 = f ^ ((u32)(((int)f) >> 31) | 0x80000000u);
        int pos = atomicAdd(&scnt[ql], 1);
        if (pos < CAP) surv[ql][pos] = ((u64)m32 << 32) | (u32)j0;
      }
      if (d2.y <= Tf[qi]) {
        float de = dist_exact(qc[qi], cxy.y, cxy.w, czw.y, czw.w);
        u32 f = __float_as_uint(de);
        u32 m32 = f ^ ((u32)(((int)f) >> 31) | 0x80000000u);
        int pos = atomicAdd(&scnt[ql], 1);
        if (pos < CAP) surv[ql][pos] = ((u64)m32 << 32) | (u32)(j0 + 1);
      }
    }
  }

  // ---- exact top-16 per query (u64 bitonic), then gather — all wave-local ----
  const float* zb = z + (size_t)b * NN * 64;
#pragma unroll 1
  for (int qi = 0; qi < QW; ++qi) {
    int ql = w * QW + qi;
    int n = scnt[ql]; if (n > CAP) n = CAP;
    u64 v = (lane < n) ? surv[ql][lane] : ~0ull;
#pragma unroll
    for (int k = 2; k <= 64; k <<= 1) {
#pragma unroll
      for (int jm = k >> 1; jm >= 1; jm >>= 1) {
        u64 o = shfl_xor_u64(v, jm);
        bool keepmin = ((lane & jm) == 0) == ((lane & k) == 0);
        u64 mn = min_u64(v, o);
        u64 mx = (v < o) ? o : v;
        v = keepmin ? mn : mx;
      }
    }
    if (lane < 16) sidx[ql][lane] = (int)(v & 0xFFFFFFFFull);
  }
#pragma unroll 1
  for (int qi = 0; qi < QW; ++qi) {
    int ql = w * QW + qi;
    const int* id = sidx[ql];            // same-wave LDS, program-order safe
    float m = -3.402823466e+38f;
#pragma unroll
    for (int k = 0; k < 16; ++k)
      m = fmaxf(m, zb[(size_t)id[k] * 64 + lane]);   // coalesced 256B row
    ys[lane][ql] = m;
  }
  __syncthreads();   // only barrier: transpose for coalesced store
  int i0 = qbase & (NN - 1);
#pragma unroll
  for (int r = 0; r < 4; ++r) {
    int e = r * 256 + t;
    int o = e >> 4, ql = e & 15;
    y[((size_t)b * 64 + o) * NN + i0 + ql] = ys[o][ql];
  }
}

extern "C" void kernel_launch(void* const* d_in, const int* in_sizes, int n_in,
                              void* d_out, int out_size, void* d_ws, size_t ws_size,
                              hipStream_t stream) {
  const float* x      = (const float*)d_in[0];   // [B,64,N]
  const float* coords = (const float*)d_in[1];   // [B,3,N]
  const float* W      = (const float*)d_in[2];   // [64,64]
  float* y = (float*)d_out;                      // [B,64,N] then coords

  char* ws = (char*)d_ws;
  float4* cpxy = (float4*)ws;                    // 256 KB
  float4* cpzw = (float4*)(ws + (1u << 18));     // 256 KB
  float*  z    = (float*)(ws + (1u << 20));      // 8 MB

  float* ycoords = y + (size_t)BB * 64 * NN;

  fused_prep_zmat<<<1024 + 64, 256, 0, stream>>>(x, W, coords, z, cpxy, cpzw, ycoords);
  knn_gather<<<BB * NN / QB, 256, 0, stream>>>(cpxy, cpzw, z, y);
}

// Round 10
// 196.359 us; speedup vs baseline: 6.1245x; 1.0005x over previous
//
#include <hip/hip_runtime.h>

#define BB 4
#define NN 8192
#define QW 8          // queries per wave (wave-independent)
#define QB 32         // queries per block (4 waves)
#define CAP 64        // survivor capacity per query
#define NPAIRS 4096   // candidate pairs per batch (N/2)

typedef unsigned long long u64;
typedef unsigned int u32;
typedef float v2f __attribute__((ext_vector_type(2)));

__device__ __forceinline__ u64 shfl_xor_u64(u64 v, int m) {
  u32 lo = (u32)v, hi = (u32)(v >> 32);
  lo = (u32)__shfl_xor((int)lo, m, 64);
  hi = (u32)__shfl_xor((int)hi, m, 64);
  return ((u64)hi << 32) | lo;
}
__device__ __forceinline__ u64 min_u64(u64 a, u64 b) { return a < b ? a : b; }
// force wave-uniform value into an SGPR (frees VGPRs; compiler can't prove uniformity)
__device__ __forceinline__ float rfl(float x) {
  return __int_as_float(__builtin_amdgcn_readfirstlane(__float_as_int(x)));
}

// fast filter distance: contracted pk math (|d' - d_exact| <= ~3e-5, covered by slack)
__device__ __forceinline__ v2f dist2_fast(float qx, float qy, float qz, float qw,
                                          v2f cx2, v2f cy2, v2f cz2, v2f cw2) {
#pragma clang fp contract(fast)
  return (qw + cw2) - 2.0f * (qx * cx2 + qy * cy2 + qz * cz2);
}

// np-exact distance (bit-matches reference; fma(-2,..) == t-2*inner exactly)
__device__ __forceinline__ float dist_exact(float qx, float qy, float qz, float qw,
                                            float cx, float cy, float cz, float cw) {
#pragma clang fp contract(off)
  float inner = qx * cx;
  inner = inner + qy * cy;
  inner = inner + qz * cz;
  float tt = qw + cw;
  return __builtin_fmaf(-2.0f, inner, tt);
}

// ---- fused: zmat (blocks 0..1023, 32-j tiles) + coords prep (blocks 1024..1087) ----
__global__ void fused_prep_zmat(const float* __restrict__ x, const float* __restrict__ W,
                                const float* __restrict__ coords,
                                float* __restrict__ z,
                                float4* __restrict__ cpxy, float4* __restrict__ cpzw,
                                float* __restrict__ ycoords) {
#pragma clang fp contract(off)
  __shared__ float Ws[64 * 65];
  __shared__ float xs[64 * 32];
  int t = threadIdx.x;
  if (blockIdx.x < 1024) {
    int blk = blockIdx.x;
    int b = blk >> 8;                 // 256 blocks per batch
    int j0 = (blk & 255) * 32;
    for (int r = t; r < 4096; r += 256) Ws[(r >> 6) * 65 + (r & 63)] = W[r];
    const float* xb = x + (size_t)b * 64 * NN;
    for (int r = 0; r < 8; ++r) {
      int idx = t + r * 256;
      int c = idx >> 5, j = idx & 31;
      xs[c * 32 + j] = xb[(size_t)c * NN + j0 + j];
    }
    __syncthreads();
    int o = t & 63, jb = (t >> 6) * 8;
    float acc[8];
#pragma unroll
    for (int m = 0; m < 8; ++m) acc[m] = 0.f;
    for (int c = 0; c < 64; ++c) {
      float w = Ws[o * 65 + c];
#pragma unroll
      for (int m = 0; m < 8; ++m) acc[m] = __builtin_fmaf(w, xs[c * 32 + jb + m], acc[m]);
    }
#pragma unroll
    for (int m = 0; m < 8; ++m)
      z[((size_t)b * NN + j0 + jb + m) * 64 + o] = acc[m];
  } else {
    int t2 = (blockIdx.x - 1024) * 256 + t;   // [0, 16384) candidate pairs
    int b = t2 >> 12;
    int pl = t2 & 4095;
    int j0 = 2 * pl;
    const float* cb = coords + (size_t)b * 3 * NN;
    float x0 = cb[j0],          x1 = cb[j0 + 1];
    float y0 = cb[NN + j0],     y1 = cb[NN + j0 + 1];
    float z0 = cb[2 * NN + j0], z1 = cb[2 * NN + j0 + 1];
    float sq0 = (x0 * x0 + y0 * y0) + z0 * z0;   // np-exact sequential fp32
    float sq1 = (x1 * x1 + y1 * y1) + z1 * z1;
    float4 pxy; pxy.x = x0; pxy.y = x1; pxy.z = y0; pxy.w = y1;
    float4 pzw; pzw.x = z0; pzw.y = z1; pzw.z = sq0; pzw.w = sq1;
    cpxy[(size_t)b * NPAIRS + pl] = pxy;
    cpzw[(size_t)b * NPAIRS + pl] = pzw;
#pragma unroll
    for (int r = 0; r < 6; ++r)
      ycoords[r * 16384 + t2] = coords[r * 16384 + t2];  // coords passthrough
  }
}

// ---- KNN: wave = 8 queries (SGPR-uniform coords), full scan; + fused gather ----
// R8: (256,8) forced VGPR 32 -> 3.4 GB spill. Keep (256,4): cap 128, natural ~50-60.
__global__ void __launch_bounds__(256, 4) knn_gather(const float4* __restrict__ cpxy,
                                                     const float4* __restrict__ cpzw,
                                                     const float* __restrict__ z,
                                                     float* __restrict__ y) {
  __shared__ u64 surv[QB][CAP];     // 16 KB
  __shared__ int scnt[QB];
  __shared__ int sidx[QB][16];      // 2 KB
  __shared__ float ys[64][QB + 1];  // 8.25 KB
  int t = threadIdx.x;
  int w = t >> 6, lane = t & 63;
  int qbase = blockIdx.x * QB;
  int b = qbase >> 13;
  const float4* pxy = cpxy + (size_t)b * NPAIRS;
  const float4* pzw = cpzw + (size_t)b * NPAIRS;

  if (lane < QW) scnt[w * QW + lane] = 0;   // wave-local, no barrier needed

  // query coords -> SGPRs (wave-uniform)
  float qx[QW], qy[QW], qz[QW], qw[QW];
#pragma unroll
  for (int qi = 0; qi < QW; ++qi) {
    int qloc = (qbase & (NN - 1)) + w * QW + qi;
    float4 a  = pxy[qloc >> 1];
    float4 bz = pzw[qloc >> 1];
    int par = qloc & 1;
    qx[qi] = rfl(par ? a.y : a.x);
    qy[qi] = rfl(par ? a.w : a.z);
    qz[qi] = rfl(par ? bz.y : bz.x);
    qw[qi] = rfl(par ? bz.w : bz.z);
  }

  // ---- pass A: per-lane min of fast distance over all candidates ----
  v2f bestd[QW];
#pragma unroll
  for (int qi = 0; qi < QW; ++qi) bestd[qi] = (v2f){3.402823466e+38f, 3.402823466e+38f};

#pragma unroll 2
  for (int s = 0; s < NPAIRS / 64; ++s) {
    float4 cxy = pxy[s * 64 + lane];   // {x0,x1,y0,y1}
    float4 czw = pzw[s * 64 + lane];   // {z0,z1,sq0,sq1}
    v2f cx2 = {cxy.x, cxy.y}, cy2 = {cxy.z, cxy.w};
    v2f cz2 = {czw.x, czw.y}, cw2 = {czw.z, czw.w};
#pragma unroll
    for (int qi = 0; qi < QW; ++qi) {
      v2f d2 = dist2_fast(qx[qi], qy[qi], qz[qi], qw[qi], cx2, cy2, cz2, cw2);
      bestd[qi].x = fminf(bestd[qi].x, d2.x);
      bestd[qi].y = fminf(bestd[qi].y, d2.y);
    }
  }

  // ---- threshold: 16th smallest of 64 per-lane minima + slack -> SGPR ----
  float Tf[QW];
#pragma unroll 1
  for (int qi = 0; qi < QW; ++qi) {
    float v = fminf(bestd[qi].x, bestd[qi].y);
#pragma unroll
    for (int k = 2; k <= 64; k <<= 1) {
#pragma unroll
      for (int jm = k >> 1; jm >= 1; jm >>= 1) {
        float o = __shfl_xor(v, jm, 64);
        bool keepmin = ((lane & jm) == 0) == ((lane & k) == 0);
        v = keepmin ? fminf(v, o) : fmaxf(v, o);
      }
    }
    float t16 = __shfl(v, 15, 64);           // full-wave shuffle (R6 lesson)
    Tf[qi] = rfl(t16 * 1.000001f + 1e-3f);   // slack >> 2*filter-rounding
  }

  // ---- pass B: fast filter, np-exact key only for survivors ----
#pragma unroll 2
  for (int s = 0; s < NPAIRS / 64; ++s) {
    float4 cxy = pxy[s * 64 + lane];
    float4 czw = pzw[s * 64 + lane];
    v2f cx2 = {cxy.x, cxy.y}, cy2 = {cxy.z, cxy.w};
    v2f cz2 = {czw.x, czw.y}, cw2 = {czw.z, czw.w};
    int j0 = (s * 64 + lane) * 2;
#pragma unroll
    for (int qi = 0; qi < QW; ++qi) {
      v2f d2 = dist2_fast(qx[qi], qy[qi], qz[qi], qw[qi], cx2, cy2, cz2, cw2);
      int ql = w * QW + qi;
      if (fminf(d2.x, d2.y) <= Tf[qi]) {     // rare outer gate
        if (d2.x <= Tf[qi]) {
          float de = dist_exact(qx[qi], qy[qi], qz[qi], qw[qi], cxy.x, cxy.z, czw.x, czw.z);
          u32 f = __float_as_uint(de);
          u32 m32 = f ^ ((u32)(((int)f) >> 31) | 0x80000000u);
          int pos = atomicAdd(&scnt[ql], 1);
          if (pos < CAP) surv[ql][pos] = ((u64)m32 << 32) | (u32)j0;
        }
        if (d2.y <= Tf[qi]) {
          float de = dist_exact(qx[qi], qy[qi], qz[qi], qw[qi], cxy.y, cxy.w, czw.y, czw.w);
          u32 f = __float_as_uint(de);
          u32 m32 = f ^ ((u32)(((int)f) >> 31) | 0x80000000u);
          int pos = atomicAdd(&scnt[ql], 1);
          if (pos < CAP) surv[ql][pos] = ((u64)m32 << 32) | (u32)(j0 + 1);
        }
      }
    }
  }

  // ---- exact top-16 per query (u64 bitonic), then gather — all wave-local ----
  const float* zb = z + (size_t)b * NN * 64;
#pragma unroll 1
  for (int qi = 0; qi < QW; ++qi) {
    int ql = w * QW + qi;
    int n = scnt[ql]; if (n > CAP) n = CAP;
    u64 v = (lane < n) ? surv[ql][lane] : ~0ull;
#pragma unroll
    for (int k = 2; k <= 64; k <<= 1) {
#pragma unroll
      for (int jm = k >> 1; jm >= 1; jm >>= 1) {
        u64 o = shfl_xor_u64(v, jm);
        bool keepmin = ((lane & jm) == 0) == ((lane & k) == 0);
        u64 mn = min_u64(v, o);
        u64 mx = (v < o) ? o : v;
        v = keepmin ? mn : mx;
      }
    }
    if (lane < 16) sidx[ql][lane] = (int)(v & 0xFFFFFFFFull);
  }
#pragma unroll 1
  for (int qi = 0; qi < QW; ++qi) {
    int ql = w * QW + qi;
    const int* id = sidx[ql];            // same-wave LDS, program-order safe
    float m = -3.402823466e+38f;
#pragma unroll
    for (int k = 0; k < 16; ++k)
      m = fmaxf(m, zb[(size_t)id[k] * 64 + lane]);   // coalesced 256B row
    ys[lane][ql] = m;
  }
  __syncthreads();   // only barrier: transpose for coalesced store
  int i0 = qbase & (NN - 1);
#pragma unroll
  for (int r = 0; r < 8; ++r) {
    int e = r * 256 + t;
    int o = e >> 5, ql = e & 31;
    y[((size_t)b * 64 + o) * NN + i0 + ql] = ys[o][ql];
  }
}

extern "C" void kernel_launch(void* const* d_in, const int* in_sizes, int n_in,
                              void* d_out, int out_size, void* d_ws, size_t ws_size,
                              hipStream_t stream) {
  const float* x      = (const float*)d_in[0];   // [B,64,N]
  const float* coords = (const float*)d_in[1];   // [B,3,N]
  const float* W      = (const float*)d_in[2];   // [64,64]
  float* y = (float*)d_out;                      // [B,64,N] then coords

  char* ws = (char*)d_ws;
  float4* cpxy = (float4*)ws;                    // 256 KB
  float4* cpzw = (float4*)(ws + (1u << 18));     // 256 KB
  float*  z    = (float*)(ws + (1u << 20));      // 8 MB

  float* ycoords = y + (size_t)BB * 64 * NN;

  fused_prep_zmat<<<1024 + 64, 256, 0, stream>>>(x, W, coords, z, cpxy, cpzw, ycoords);
  knn_gather<<<BB * NN / QB, 256, 0, stream>>>(cpxy, cpzw, z, y);
}

// Round 11
// 191.869 us; speedup vs baseline: 6.2678x; 1.0234x over previous
//
#include <hip/hip_runtime.h>

#define BB 4
#define NN 8192
#define QW 8          // queries per wave (wave-independent)
#define QB 32         // queries per block (4 waves)
#define CAP 64        // survivor capacity per query
#define NPAIRS 4096   // candidate pairs per batch (N/2)

typedef unsigned long long u64;
typedef unsigned int u32;
typedef float v2f __attribute__((ext_vector_type(2)));

__device__ __forceinline__ u64 shfl_xor_u64(u64 v, int m) {
  u32 lo = (u32)v, hi = (u32)(v >> 32);
  lo = (u32)__shfl_xor((int)lo, m, 64);
  hi = (u32)__shfl_xor((int)hi, m, 64);
  return ((u64)hi << 32) | lo;
}
__device__ __forceinline__ u64 min_u64(u64 a, u64 b) { return a < b ? a : b; }
// force wave-uniform value into an SGPR
__device__ __forceinline__ float rfl(float x) {
  return __int_as_float(__builtin_amdgcn_readfirstlane(__float_as_int(x)));
}

// fast filter distance: contracted pk math (|d' - d_exact| <= ~3e-5, covered by slack)
__device__ __forceinline__ v2f dist2_fast(float qx, float qy, float qz, float qw,
                                          v2f cx2, v2f cy2, v2f cz2, v2f cw2) {
#pragma clang fp contract(fast)
  return (qw + cw2) - 2.0f * (qx * cx2 + qy * cy2 + qz * cz2);
}

// np-exact distance (bit-matches reference; fma(-2,..) == t-2*inner exactly)
__device__ __forceinline__ float dist_exact(float qx, float qy, float qz, float qw,
                                            float cx, float cy, float cz, float cw) {
#pragma clang fp contract(off)
  float inner = qx * cx;
  inner = inner + qy * cy;
  inner = inner + qz * cz;
  float tt = qw + cw;
  return __builtin_fmaf(-2.0f, inner, tt);
}

// ---- fused: zmat (blocks 0..1023, 32-j tiles) + coords prep (blocks 1024..1087) ----
__global__ void fused_prep_zmat(const float* __restrict__ x, const float* __restrict__ W,
                                const float* __restrict__ coords,
                                float* __restrict__ z,
                                float4* __restrict__ cpxy, float4* __restrict__ cpzw,
                                float* __restrict__ ycoords) {
#pragma clang fp contract(off)
  __shared__ float Ws[64 * 65];
  __shared__ float xs[64 * 32];
  int t = threadIdx.x;
  if (blockIdx.x < 1024) {
    int blk = blockIdx.x;
    int b = blk >> 8;                 // 256 blocks per batch
    int j0 = (blk & 255) * 32;
    for (int r = t; r < 4096; r += 256) Ws[(r >> 6) * 65 + (r & 63)] = W[r];
    const float* xb = x + (size_t)b * 64 * NN;
    for (int r = 0; r < 8; ++r) {
      int idx = t + r * 256;
      int c = idx >> 5, j = idx & 31;
      xs[c * 32 + j] = xb[(size_t)c * NN + j0 + j];
    }
    __syncthreads();
    int o = t & 63, jb = (t >> 6) * 8;
    float acc[8];
#pragma unroll
    for (int m = 0; m < 8; ++m) acc[m] = 0.f;
    for (int c = 0; c < 64; ++c) {
      float w = Ws[o * 65 + c];
#pragma unroll
      for (int m = 0; m < 8; ++m) acc[m] = __builtin_fmaf(w, xs[c * 32 + jb + m], acc[m]);
    }
#pragma unroll
    for (int m = 0; m < 8; ++m)
      z[((size_t)b * NN + j0 + jb + m) * 64 + o] = acc[m];
  } else {
    int t2 = (blockIdx.x - 1024) * 256 + t;   // [0, 16384) candidate pairs
    int b = t2 >> 12;
    int pl = t2 & 4095;
    int j0 = 2 * pl;
    const float* cb = coords + (size_t)b * 3 * NN;
    float x0 = cb[j0],          x1 = cb[j0 + 1];
    float y0 = cb[NN + j0],     y1 = cb[NN + j0 + 1];
    float z0 = cb[2 * NN + j0], z1 = cb[2 * NN + j0 + 1];
    float sq0 = (x0 * x0 + y0 * y0) + z0 * z0;   // np-exact sequential fp32
    float sq1 = (x1 * x1 + y1 * y1) + z1 * z1;
    float4 pxy; pxy.x = x0; pxy.y = x1; pxy.z = y0; pxy.w = y1;
    float4 pzw; pzw.x = z0; pzw.y = z1; pzw.z = sq0; pzw.w = sq1;
    cpxy[(size_t)b * NPAIRS + pl] = pxy;
    cpzw[(size_t)b * NPAIRS + pl] = pzw;
#pragma unroll
    for (int r = 0; r < 6; ++r)
      ycoords[r * 16384 + t2] = coords[r * 16384 + t2];  // coords passthrough
  }
}

// ---- KNN: wave = 8 queries, full scan; deferred exact keys; + fused gather ----
// R8: (256,8) forced VGPR 32 -> 3.4 GB spill. Keep (256,4): cap 128.
__global__ void __launch_bounds__(256, 4) knn_gather(const float4* __restrict__ cpxy,
                                                     const float4* __restrict__ cpzw,
                                                     const float* __restrict__ z,
                                                     float* __restrict__ y) {
  __shared__ u32 survj[QB][CAP];    // 8 KB (index only; exact key deferred)
  __shared__ int scnt[QB];
  __shared__ int sidx[QB][16];      // 2 KB
  __shared__ float ys[64][QB + 1];  // 8.25 KB
  int t = threadIdx.x;
  int w = t >> 6, lane = t & 63;
  int qbase = blockIdx.x * QB;
  int b = qbase >> 13;
  const float4* pxy = cpxy + (size_t)b * NPAIRS;
  const float4* pzw = cpzw + (size_t)b * NPAIRS;

  if (lane < QW) scnt[w * QW + lane] = 0;   // wave-local, no barrier needed

  // query coords -> SGPRs (wave-uniform)
  float qx[QW], qy[QW], qz[QW], qw[QW];
#pragma unroll
  for (int qi = 0; qi < QW; ++qi) {
    int qloc = (qbase & (NN - 1)) + w * QW + qi;
    float4 a  = pxy[qloc >> 1];
    float4 bz = pzw[qloc >> 1];
    int par = qloc & 1;
    qx[qi] = rfl(par ? a.y : a.x);
    qy[qi] = rfl(par ? a.w : a.z);
    qz[qi] = rfl(par ? bz.y : bz.x);
    qw[qi] = rfl(par ? bz.w : bz.z);
  }

  // ---- pass A: per-lane min of fast distance, software-pipelined loads ----
  v2f bestd[QW];
#pragma unroll
  for (int qi = 0; qi < QW; ++qi) bestd[qi] = (v2f){3.402823466e+38f, 3.402823466e+38f};

  {
    float4 nxy = pxy[lane], nzw = pzw[lane];   // prefetch s=0
#pragma unroll 2
    for (int s = 0; s < NPAIRS / 64; ++s) {
      float4 cxy = nxy, czw = nzw;
      int sn = (s + 1 < NPAIRS / 64) ? s + 1 : s;
      nxy = pxy[sn * 64 + lane];               // prefetch s+1 before compute
      nzw = pzw[sn * 64 + lane];
      v2f cx2 = {cxy.x, cxy.y}, cy2 = {cxy.z, cxy.w};
      v2f cz2 = {czw.x, czw.y}, cw2 = {czw.z, czw.w};
#pragma unroll
      for (int qi = 0; qi < QW; ++qi) {
        v2f d2 = dist2_fast(qx[qi], qy[qi], qz[qi], qw[qi], cx2, cy2, cz2, cw2);
        bestd[qi].x = fminf(bestd[qi].x, d2.x);
        bestd[qi].y = fminf(bestd[qi].y, d2.y);
      }
    }
  }

  // ---- threshold: 16th smallest of 64 per-lane minima + slack -> SGPR ----
  float Tf[QW];
#pragma unroll 1
  for (int qi = 0; qi < QW; ++qi) {
    float v = fminf(bestd[qi].x, bestd[qi].y);
#pragma unroll
    for (int k = 2; k <= 64; k <<= 1) {
#pragma unroll
      for (int jm = k >> 1; jm >= 1; jm >>= 1) {
        float o = __shfl_xor(v, jm, 64);
        bool keepmin = ((lane & jm) == 0) == ((lane & k) == 0);
        v = keepmin ? fminf(v, o) : fmaxf(v, o);
      }
    }
    float t16 = __shfl(v, 15, 64);           // full-wave shuffle (R6 lesson)
    Tf[qi] = rfl(t16 * 1.000001f + 1e-3f);   // slack >> 2*filter-rounding
  }

  // ---- pass B: fast filter; fires store INDEX ONLY (exact key deferred) ----
  {
    float4 nxy = pxy[lane], nzw = pzw[lane];
#pragma unroll 2
    for (int s = 0; s < NPAIRS / 64; ++s) {
      float4 cxy = nxy, czw = nzw;
      int sn = (s + 1 < NPAIRS / 64) ? s + 1 : s;
      nxy = pxy[sn * 64 + lane];
      nzw = pzw[sn * 64 + lane];
      v2f cx2 = {cxy.x, cxy.y}, cy2 = {cxy.z, cxy.w};
      v2f cz2 = {czw.x, czw.y}, cw2 = {czw.z, czw.w};
      int j0 = (s * 64 + lane) * 2;
#pragma unroll
      for (int qi = 0; qi < QW; ++qi) {
        v2f d2 = dist2_fast(qx[qi], qy[qi], qz[qi], qw[qi], cx2, cy2, cz2, cw2);
        int ql = w * QW + qi;
        if (fminf(d2.x, d2.y) <= Tf[qi]) {     // rare outer gate (~19/query total)
          if (d2.x <= Tf[qi]) {
            int pos = atomicAdd(&scnt[ql], 1);
            if (pos < CAP) survj[ql][pos] = (u32)j0;
          }
          if (d2.y <= Tf[qi]) {
            int pos = atomicAdd(&scnt[ql], 1);
            if (pos < CAP) survj[ql][pos] = (u32)(j0 + 1);
          }
        }
      }
    }
  }

  // ---- epilogue: rebuild exact keys for survivors, u64 bitonic, gather ----
  const float* zb = z + (size_t)b * NN * 64;
#pragma unroll 1
  for (int qi = 0; qi < QW; ++qi) {
    int ql = w * QW + qi;
    int n = scnt[ql]; if (n > CAP) n = CAP;
    u64 v = ~0ull;
    if (lane < n) {
      int j = (int)survj[ql][lane];
      float4 cxy = pxy[j >> 1];                // scattered L2 re-load (few)
      float4 czw = pzw[j >> 1];
      int par = j & 1;
      float cx = par ? cxy.y : cxy.x;
      float cy = par ? cxy.w : cxy.z;
      float cz = par ? czw.y : czw.x;
      float cw = par ? czw.w : czw.z;
      float de = dist_exact(qx[qi], qy[qi], qz[qi], qw[qi], cx, cy, cz, cw);
      u32 f = __float_as_uint(de);
      u32 m32 = f ^ ((u32)(((int)f) >> 31) | 0x80000000u);
      v = ((u64)m32 << 32) | (u32)j;
    }
#pragma unroll
    for (int k = 2; k <= 64; k <<= 1) {
#pragma unroll
      for (int jm = k >> 1; jm >= 1; jm >>= 1) {
        u64 o = shfl_xor_u64(v, jm);
        bool keepmin = ((lane & jm) == 0) == ((lane & k) == 0);
        u64 mn = min_u64(v, o);
        u64 mx = (v < o) ? o : v;
        v = keepmin ? mn : mx;
      }
    }
    if (lane < 16) sidx[ql][lane] = (int)(v & 0xFFFFFFFFull);
  }
#pragma unroll 1
  for (int qi = 0; qi < QW; ++qi) {
    int ql = w * QW + qi;
    const int* id = sidx[ql];            // same-wave LDS, program-order safe
    float m = -3.402823466e+38f;
#pragma unroll
    for (int k = 0; k < 16; ++k)
      m = fmaxf(m, zb[(size_t)id[k] * 64 + lane]);   // coalesced 256B row
    ys[lane][ql] = m;
  }
  __syncthreads();   // only barrier: transpose for coalesced store
  int i0 = qbase & (NN - 1);
#pragma unroll
  for (int r = 0; r < 8; ++r) {
    int e = r * 256 + t;
    int o = e >> 5, ql = e & 31;
    y[((size_t)b * 64 + o) * NN + i0 + ql] = ys[o][ql];
  }
}

extern "C" void kernel_launch(void* const* d_in, const int* in_sizes, int n_in,
                              void* d_out, int out_size, void* d_ws, size_t ws_size,
                              hipStream_t stream) {
  const float* x      = (const float*)d_in[0];   // [B,64,N]
  const float* coords = (const float*)d_in[1];   // [B,3,N]
  const float* W      = (const float*)d_in[2];   // [64,64]
  float* y = (float*)d_out;                      // [B,64,N] then coords

  char* ws = (char*)d_ws;
  float4* cpxy = (float4*)ws;                    // 256 KB
  float4* cpzw = (float4*)(ws + (1u << 18));     // 256 KB
  float*  z    = (float*)(ws + (1u << 20));      // 8 MB

  float* ycoords = y + (size_t)BB * 64 * NN;

  fused_prep_zmat<<<1024 + 64, 256, 0, stream>>>(x, W, coords, z, cpxy, cpzw, ycoords);
  knn_gather<<<BB * NN / QB, 256, 0, stream>>>(cpxy, cpzw, z, y);
}

// Round 12
// 172.888 us; speedup vs baseline: 6.9560x; 1.1098x over previous
//
#include <hip/hip_runtime.h>

#define BB 4
#define NN 8192
#define QW 8          // queries per wave (wave-independent)
#define QB 32         // queries per block (4 waves)
#define CAP 64        // survivor capacity per query

typedef unsigned long long u64;
typedef unsigned int u32;

__device__ __forceinline__ u64 shfl_xor_u64(u64 v, int m) {
  u32 lo = (u32)v, hi = (u32)(v >> 32);
  lo = (u32)__shfl_xor((int)lo, m, 64);
  hi = (u32)__shfl_xor((int)hi, m, 64);
  return ((u64)hi << 32) | lo;
}
__device__ __forceinline__ u64 min_u64(u64 a, u64 b) { return a < b ? a : b; }
// force wave-uniform value into an SGPR
__device__ __forceinline__ float rfl(float x) {
  return __int_as_float(__builtin_amdgcn_readfirstlane(__float_as_int(x)));
}

// filter statistic: d~ = sq_c - 2*q.c  (= d_exact - qw, +- ~3ulp). 3 fma.
__device__ __forceinline__ float dtilde(float qx, float qy, float qz, float4 c) {
  return __builtin_fmaf(qx, c.x, __builtin_fmaf(qy, c.y, __builtin_fmaf(qz, c.z, c.w)));
}

// np-exact distance (bit-matches reference; fma(-2,..) == t-2*inner exactly)
__device__ __forceinline__ float dist_exact(float qx, float qy, float qz, float qw,
                                            float cx, float cy, float cz, float cw) {
#pragma clang fp contract(off)
  float inner = qx * cx;
  inner = inner + qy * cy;
  inner = inner + qz * cz;
  float tt = qw + cw;
  return __builtin_fmaf(-2.0f, inner, tt);
}

// ---- fused: zmat (blocks 0..1023) + coords prep c'=(-2x,-2y,-2z,sq) (1024..1151) ----
__global__ void fused_prep_zmat(const float* __restrict__ x, const float* __restrict__ W,
                                const float* __restrict__ coords,
                                float* __restrict__ z, float4* __restrict__ c4p,
                                float* __restrict__ ycoords) {
#pragma clang fp contract(off)
  __shared__ float Ws[64 * 65];
  __shared__ float xs[64 * 32];
  int t = threadIdx.x;
  if (blockIdx.x < 1024) {
    int blk = blockIdx.x;
    int b = blk >> 8;                 // 256 blocks per batch
    int j0 = (blk & 255) * 32;
    for (int r = t; r < 4096; r += 256) Ws[(r >> 6) * 65 + (r & 63)] = W[r];
    const float* xb = x + (size_t)b * 64 * NN;
    for (int r = 0; r < 8; ++r) {
      int idx = t + r * 256;
      int c = idx >> 5, j = idx & 31;
      xs[c * 32 + j] = xb[(size_t)c * NN + j0 + j];
    }
    __syncthreads();
    int o = t & 63, jb = (t >> 6) * 8;
    float acc[8];
#pragma unroll
    for (int m = 0; m < 8; ++m) acc[m] = 0.f;
    for (int c = 0; c < 64; ++c) {
      float w = Ws[o * 65 + c];
#pragma unroll
      for (int m = 0; m < 8; ++m) acc[m] = __builtin_fmaf(w, xs[c * 32 + jb + m], acc[m]);
    }
#pragma unroll
    for (int m = 0; m < 8; ++m)
      z[((size_t)b * NN + j0 + jb + m) * 64 + o] = acc[m];
  } else {
    int t2 = (blockIdx.x - 1024) * 256 + t;   // [0, B*N) candidates
    int b = t2 >> 13;
    int i = t2 & (NN - 1);
    const float* cb = coords + (size_t)b * 3 * NN;
    float cx = cb[i];
    float cy = cb[NN + i];
    float cz = cb[2 * NN + i];
    float sq = (cx * cx + cy * cy) + cz * cz;   // np-exact sequential fp32
    float4 v; v.x = -2.0f * cx; v.y = -2.0f * cy; v.z = -2.0f * cz; v.w = sq;
    c4p[t2] = v;                                 // x recovered exactly via *-0.5
#pragma unroll
    for (int r = 0; r < 3; ++r)                  // flat coords passthrough
      ycoords[r * (BB * NN) + t2] = coords[r * (BB * NN) + t2];
  }
}

// ---- KNN: wave = 8 queries, 2-pass d~ filter (3 fma/pair), exact epilogue, gather ----
// R8 lesson: (256,8) forced VGPR 32 -> 3.4 GB spill. Keep (256,4): cap 128.
__global__ void __launch_bounds__(256, 4) knn_gather(const float4* __restrict__ c4p,
                                                     const float* __restrict__ z,
                                                     float* __restrict__ y) {
  __shared__ u32 survj[QB][CAP];    // 8 KB (index only; exact key deferred)
  __shared__ int scnt[QB];
  __shared__ int sidx[QB][16];      // 2 KB
  __shared__ float ys[64][QB + 1];  // 8.25 KB
  int t = threadIdx.x;
  int w = t >> 6, lane = t & 63;
  int qbase = blockIdx.x * QB;
  int b = qbase >> 13;
  const float4* cp = c4p + (size_t)b * NN;

  if (lane < QW) scnt[w * QW + lane] = 0;   // wave-local, no barrier needed

  // query raw coords -> SGPRs (exact *-0.5 recovery from c')
  float qx[QW], qy[QW], qz[QW], qw[QW];
#pragma unroll
  for (int qi = 0; qi < QW; ++qi) {
    float4 qv = cp[(qbase & (NN - 1)) + w * QW + qi];
    qx[qi] = rfl(-0.5f * qv.x);
    qy[qi] = rfl(-0.5f * qv.y);
    qz[qi] = rfl(-0.5f * qv.z);
    qw[qi] = rfl(qv.w);
  }

  // ---- pass A: per-lane min of d~ over all candidates (3 fma + 1 min each) ----
  float best[QW];
#pragma unroll
  for (int qi = 0; qi < QW; ++qi) best[qi] = 3.402823466e+38f;

#pragma unroll 4
  for (int s = 0; s < NN / 64; ++s) {
    float4 c = cp[s * 64 + lane];
#pragma unroll
    for (int qi = 0; qi < QW; ++qi)
      best[qi] = fminf(best[qi], dtilde(qx[qi], qy[qi], qz[qi], c));
  }

  // ---- threshold: 16th smallest of 64 per-lane minima + ADDITIVE slack -> SGPR ----
  // (d~ is typically negative: multiplicative slack would shrink it)
  float Tf[QW];
#pragma unroll 1
  for (int qi = 0; qi < QW; ++qi) {
    float v = best[qi];
#pragma unroll
    for (int k = 2; k <= 64; k <<= 1) {
#pragma unroll
      for (int jm = k >> 1; jm >= 1; jm >>= 1) {
        float o = __shfl_xor(v, jm, 64);
        bool keepmin = ((lane & jm) == 0) == ((lane & k) == 0);
        v = keepmin ? fminf(v, o) : fmaxf(v, o);
      }
    }
    float t16 = __shfl(v, 15, 64);     // full-wave shuffle (R6 lesson)
    Tf[qi] = rfl(t16 + 1e-3f);         // slack >> 2*(d~ vs d-qw rounding ~1e-5)
  }

  // ---- pass B: same d~; fires store INDEX ONLY ----
#pragma unroll 4
  for (int s = 0; s < NN / 64; ++s) {
    float4 c = cp[s * 64 + lane];
    int j = s * 64 + lane;
#pragma unroll
    for (int qi = 0; qi < QW; ++qi) {
      float dt = dtilde(qx[qi], qy[qi], qz[qi], c);
      if (dt <= Tf[qi]) {                        // ~19/query total
        int ql = w * QW + qi;
        int pos = atomicAdd(&scnt[ql], 1);
        if (pos < CAP) survj[ql][pos] = (u32)j;
      }
    }
  }

  // ---- epilogue: np-exact keys for survivors, u64 bitonic, gather ----
  const float* zb = z + (size_t)b * NN * 64;
#pragma unroll 1
  for (int qi = 0; qi < QW; ++qi) {
    int ql = w * QW + qi;
    int n = scnt[ql]; if (n > CAP) n = CAP;
    u64 v = ~0ull;
    if (lane < n) {
      int j = (int)survj[ql][lane];
      float4 cj = cp[j];                         // scattered L2 re-load (few)
      float de = dist_exact(qx[qi], qy[qi], qz[qi], qw[qi],
                            -0.5f * cj.x, -0.5f * cj.y, -0.5f * cj.z, cj.w);
      u32 f = __float_as_uint(de);
      u32 m32 = f ^ ((u32)(((int)f) >> 31) | 0x80000000u);
      v = ((u64)m32 << 32) | (u32)j;
    }
#pragma unroll
    for (int k = 2; k <= 64; k <<= 1) {
#pragma unroll
      for (int jm = k >> 1; jm >= 1; jm >>= 1) {
        u64 o = shfl_xor_u64(v, jm);
        bool keepmin = ((lane & jm) == 0) == ((lane & k) == 0);
        u64 mn = min_u64(v, o);
        u64 mx = (v < o) ? o : v;
        v = keepmin ? mn : mx;
      }
    }
    if (lane < 16) sidx[ql][lane] = (int)(v & 0xFFFFFFFFull);
  }
#pragma unroll 1
  for (int qi = 0; qi < QW; ++qi) {
    int ql = w * QW + qi;
    const int* id = sidx[ql];            // same-wave LDS, program-order safe
    float m = -3.402823466e+38f;
#pragma unroll
    for (int k = 0; k < 16; ++k)
      m = fmaxf(m, zb[(size_t)id[k] * 64 + lane]);   // coalesced 256B row
    ys[lane][ql] = m;
  }
  __syncthreads();   // only barrier: transpose for coalesced store
  int i0 = qbase & (NN - 1);
#pragma unroll
  for (int r = 0; r < 8; ++r) {
    int e = r * 256 + t;
    int o = e >> 5, ql = e & 31;
    y[((size_t)b * 64 + o) * NN + i0 + ql] = ys[o][ql];
  }
}

extern "C" void kernel_launch(void* const* d_in, const int* in_sizes, int n_in,
                              void* d_out, int out_size, void* d_ws, size_t ws_size,
                              hipStream_t stream) {
  const float* x      = (const float*)d_in[0];   // [B,64,N]
  const float* coords = (const float*)d_in[1];   // [B,3,N]
  const float* W      = (const float*)d_in[2];   // [64,64]
  float* y = (float*)d_out;                      // [B,64,N] then coords

  char* ws = (char*)d_ws;
  float4* c4p = (float4*)ws;                     // 512 KB
  float*  z   = (float*)(ws + (1u << 20));       // 8 MB

  float* ycoords = y + (size_t)BB * 64 * NN;

  fused_prep_zmat<<<1024 + 128, 256, 0, stream>>>(x, W, coords, z, c4p, ycoords);
  knn_gather<<<BB * NN / QB, 256, 0, stream>>>(c4p, z, y);
}